// Round 1
// baseline (1494.595 us; speedup 1.0000x reference)
//
#include <hip/hip_runtime.h>
#include <math.h>

// Problem dims
constexpr int CB = 64;        // batch
constexpr int CD = 3072;      // feature dim (3*32*32)
constexpr int CN = 50000;     // train rows
constexpr int NPAD = 50048;   // 391*128, divisible by 32
constexpr int NT1 = 128;      // GEMM1 n-tile
constexpr int TK = 32;        // k-tile (both GEMMs)
constexpr int G2 = 24;        // GEMM2 split-K chunks
constexpr int NTILES = NPAD / TK;            // 1564
constexpr int KTPG = (NTILES + G2 - 1) / G2; // 66
constexpr int TD2 = 128;      // GEMM2 d-tile

// ws float offsets
constexpr int OFF_XSQ = 0;
constexpr int OFF_A = 64;
constexpr int OFF_CDENO = 128;
constexpr int OFF_CX = 192;
constexpr int OFF_CXH = 256;
constexpr int OFF_L = 320;
constexpr int OFF_NORM = 512;
constexpr size_t OFF_PART = (size_t)512 + (size_t)CB * NPAD; // 3,203,584

// ---------------- Kernel 1: coefficients + x_sq ----------------
__global__ __launch_bounds__(64) void prep_kernel(
    const float* __restrict__ x, const float* __restrict__ acp,
    const int* __restrict__ t, float* __restrict__ wsf) {
  const int b = blockIdx.x;
  const int tid = threadIdx.x;
  float s = 0.f;
  for (int i = tid; i < CD; i += 64) {
    float v = x[b * CD + i];
    s += v * v;
  }
#pragma unroll
  for (int o = 1; o < 64; o <<= 1) s += __shfl_xor(s, o);
  if (tid == 0) {
    float ac = acp[t[b]];
    float a = sqrtf(ac);
    float om = 1.0f - ac;
    float sq = sqrtf(om);
    wsf[OFF_XSQ + b] = s;
    wsf[OFF_A + b] = a;
    wsf[OFF_CDENO + b] = -0.5f / om;
    wsf[OFF_CX + b] = 1.0f / sq;
    wsf[OFF_CXH + b] = a / sq;
  }
}

// ---------------- Kernel 2: norm = coef_deno*(x_sq - 2a*cross + a^2*tr_sq) ----------------
// Tile: 64(b) x 128(n), 256 threads, per-thread 4x8, K streamed in 32-chunks.
// tr_sq computed on the fly (each block sees its train rows fully).
__global__ __launch_bounds__(256) void norm_gemm_kernel(
    const float* __restrict__ x, const float* __restrict__ train,
    float* __restrict__ wsf) {
  __shared__ float As[TK][68];    // As[k][b]
  __shared__ float Bs[TK][132];   // Bs[k][n]
  __shared__ float trsq_s[NT1];

  const int tid = threadIdx.x;
  const int n0 = blockIdx.x * NT1;
  const int tx = tid & 15;   // n group: n = 8*tx + j
  const int ty = tid >> 4;   // b group: b = 4*ty + i

  float acc[4][8];
#pragma unroll
  for (int i = 0; i < 4; i++)
#pragma unroll
    for (int j = 0; j < 8; j++) acc[i][j] = 0.f;

  float sq[4];  // train-row square partials, rows n = tid/8 + 32*i
#pragma unroll
  for (int i = 0; i < 4; i++) sq[i] = 0.f;

  for (int k0 = 0; k0 < CD; k0 += TK) {
    // stage x tile: 64 x 32 = 512 float4, 2 per thread
#pragma unroll
    for (int i = 0; i < 2; i++) {
      int f = tid + 256 * i;
      int b = f >> 3;
      int kq = f & 7;
      float4 v = *reinterpret_cast<const float4*>(&x[(size_t)b * CD + k0 + 4 * kq]);
      As[4 * kq + 0][b] = v.x;
      As[4 * kq + 1][b] = v.y;
      As[4 * kq + 2][b] = v.z;
      As[4 * kq + 3][b] = v.w;
    }
    // stage train tile: 128 x 32 = 1024 float4, 4 per thread
#pragma unroll
    for (int i = 0; i < 4; i++) {
      int f = tid + 256 * i;
      int n = f >> 3;   // 0..127
      int kq = f & 7;
      int gn = n0 + n;
      float4 v;
      if (gn < CN)
        v = *reinterpret_cast<const float4*>(&train[(size_t)gn * CD + k0 + 4 * kq]);
      else
        v = make_float4(0.f, 0.f, 0.f, 0.f);
      Bs[4 * kq + 0][n] = v.x;
      Bs[4 * kq + 1][n] = v.y;
      Bs[4 * kq + 2][n] = v.z;
      Bs[4 * kq + 3][n] = v.w;
      sq[i] += v.x * v.x + v.y * v.y + v.z * v.z + v.w * v.w;
    }
    __syncthreads();
#pragma unroll 8
    for (int k = 0; k < TK; ++k) {
      float av[4], bv[8];
      *reinterpret_cast<float4*>(av) = *reinterpret_cast<const float4*>(&As[k][4 * ty]);
      *reinterpret_cast<float4*>(bv) = *reinterpret_cast<const float4*>(&Bs[k][8 * tx]);
      *reinterpret_cast<float4*>(bv + 4) = *reinterpret_cast<const float4*>(&Bs[k][8 * tx + 4]);
#pragma unroll
      for (int i = 0; i < 4; ++i)
#pragma unroll
        for (int j = 0; j < 8; ++j) acc[i][j] = fmaf(av[i], bv[j], acc[i][j]);
    }
    __syncthreads();
  }

  // reduce tr_sq across the 8 lanes sharing each row
#pragma unroll
  for (int i = 0; i < 4; i++) {
    float s = sq[i];
    s += __shfl_xor(s, 1);
    s += __shfl_xor(s, 2);
    s += __shfl_xor(s, 4);
    if ((tid & 7) == 0) trsq_s[(tid >> 3) + 32 * i] = s;
  }
  __syncthreads();

  float trq[8];
#pragma unroll
  for (int j = 0; j < 8; j++) trq[j] = trsq_s[8 * tx + j];

#pragma unroll
  for (int i = 0; i < 4; i++) {
    int b = 4 * ty + i;
    float a_ = wsf[OFF_A + b];
    float cdeno = wsf[OFF_CDENO + b];
    float twoa = 2.f * a_;
    float asq = a_ * a_;
    float xsq = wsf[OFF_XSQ + b];
    float outv[8];
#pragma unroll
    for (int j = 0; j < 8; j++) {
      int n = n0 + 8 * tx + j;
      float nv = cdeno * (xsq - twoa * acc[i][j] + asq * trq[j]);
      outv[j] = (n < CN) ? nv : -3.0e38f;
    }
    float* dst = &wsf[OFF_NORM + (size_t)b * NPAD + n0 + 8 * tx];
    *reinterpret_cast<float4*>(dst) = *reinterpret_cast<float4*>(outv);
    *reinterpret_cast<float4*>(dst + 4) = *reinterpret_cast<float4*>(outv + 4);
  }
}

// ---------------- Kernel 3: softmax (in place -> unnormalized exp), store l ----------------
__global__ __launch_bounds__(1024) void softmax_kernel(float* __restrict__ wsf) {
  const int b = blockIdx.x;
  float* row = wsf + OFF_NORM + (size_t)b * NPAD;
  const int tid = threadIdx.x;
  const int lane = tid & 63, wid = tid >> 6;
  __shared__ float red[16];

  float m = -3.4e38f;
  for (int i = tid; i < NPAD; i += 1024) m = fmaxf(m, row[i]);
#pragma unroll
  for (int o = 1; o < 64; o <<= 1) m = fmaxf(m, __shfl_xor(m, o));
  if (lane == 0) red[wid] = m;
  __syncthreads();
  if (tid == 0) {
    float mm = red[0];
    for (int w = 1; w < 16; w++) mm = fmaxf(mm, red[w]);
    red[0] = mm;
  }
  __syncthreads();
  const float mAll = red[0];
  __syncthreads();

  float s = 0.f;
  for (int i = tid; i < NPAD; i += 1024) {
    float e = __expf(row[i] - mAll);
    row[i] = e;
    s += e;
  }
#pragma unroll
  for (int o = 1; o < 64; o <<= 1) s += __shfl_xor(s, o);
  if (lane == 0) red[wid] = s;
  __syncthreads();
  if (tid == 0) {
    float ss = 0.f;
    for (int w = 0; w < 16; w++) ss += red[w];
    wsf[OFF_L + b] = ss;
  }
}

// ---------------- Kernel 4: weighted partial = what @ train (split-K over n) ----------------
// grid (24 d-tiles, G2 chunks), tile 64(b) x 128(d), 256 threads, 4x8 per thread.
__global__ __launch_bounds__(256) void gemm2_kernel(
    const float* __restrict__ train, float* __restrict__ wsf) {
  __shared__ float Ws[TK][68];    // Ws[n][b]
  __shared__ float Ts[TK][132];   // Ts[n][d]

  const int tid = threadIdx.x;
  const int dd0 = blockIdx.x * TD2;
  const int g = blockIdx.y;
  const int kt0 = g * KTPG;
  const int kt1 = (kt0 + KTPG < NTILES) ? (kt0 + KTPG) : NTILES;
  const int tx = tid & 15;   // d group
  const int ty = tid >> 4;   // b group

  float acc[4][8];
#pragma unroll
  for (int i = 0; i < 4; i++)
#pragma unroll
    for (int j = 0; j < 8; j++) acc[i][j] = 0.f;

  for (int kt = kt0; kt < kt1; kt++) {
    const int n0 = kt * TK;
    // stage w tile: 64 b x 32 n = 512 float4, 2 per thread (transpose into [n][b])
#pragma unroll
    for (int i = 0; i < 2; i++) {
      int f = tid + 256 * i;
      int b = f >> 3;
      int nq = f & 7;
      float4 v = *reinterpret_cast<const float4*>(
          &wsf[OFF_NORM + (size_t)b * NPAD + n0 + 4 * nq]);
      Ws[4 * nq + 0][b] = v.x;
      Ws[4 * nq + 1][b] = v.y;
      Ws[4 * nq + 2][b] = v.z;
      Ws[4 * nq + 3][b] = v.w;
    }
    // stage train tile: 32 n x 128 d = 1024 float4, 4 per thread (natural layout)
#pragma unroll
    for (int i = 0; i < 4; i++) {
      int f = tid + 256 * i;
      int n = f >> 5;    // 0..31
      int dq = f & 31;
      int gn = n0 + n;
      if (gn >= CN) gn = CN - 1;  // w is 0 there; just avoid OOB
      float4 v = *reinterpret_cast<const float4*>(&train[(size_t)gn * CD + dd0 + 4 * dq]);
      *reinterpret_cast<float4*>(&Ts[n][4 * dq]) = v;
    }
    __syncthreads();
#pragma unroll 8
    for (int k = 0; k < TK; ++k) {
      float av[4], bv[8];
      *reinterpret_cast<float4*>(av) = *reinterpret_cast<const float4*>(&Ws[k][4 * ty]);
      *reinterpret_cast<float4*>(bv) = *reinterpret_cast<const float4*>(&Ts[k][8 * tx]);
      *reinterpret_cast<float4*>(bv + 4) = *reinterpret_cast<const float4*>(&Ts[k][8 * tx + 4]);
#pragma unroll
      for (int i = 0; i < 4; ++i)
#pragma unroll
        for (int j = 0; j < 8; ++j) acc[i][j] = fmaf(av[i], bv[j], acc[i][j]);
    }
    __syncthreads();
  }

#pragma unroll
  for (int i = 0; i < 4; i++) {
    int b = 4 * ty + i;
    float* dst = &wsf[OFF_PART + ((size_t)g * CB + b) * CD + dd0 + 8 * tx];
    *reinterpret_cast<float4*>(dst) = *reinterpret_cast<float4*>(&acc[i][0]);
    *reinterpret_cast<float4*>(dst + 4) = *reinterpret_cast<float4*>(&acc[i][4]);
  }
}

// ---------------- Kernel 5: reduce partials + finalize ----------------
__global__ __launch_bounds__(256) void finalize_kernel(
    const float* __restrict__ x, const float* __restrict__ wsf,
    float* __restrict__ out) {
  const int idx = blockIdx.x * 256 + threadIdx.x;  // 0..196607
  const int b = idx / CD;
  float s = 0.f;
#pragma unroll 4
  for (int g = 0; g < G2; g++) s += wsf[OFF_PART + (size_t)g * CB * CD + idx];
  const float l = wsf[OFF_L + b];
  out[idx] = wsf[OFF_CX + b] * x[idx] - (wsf[OFF_CXH + b] / l) * s;
}

extern "C" void kernel_launch(void* const* d_in, const int* in_sizes, int n_in,
                              void* d_out, int out_size, void* d_ws, size_t ws_size,
                              hipStream_t stream) {
  (void)in_sizes; (void)n_in; (void)out_size; (void)ws_size;
  const float* x = (const float*)d_in[0];
  const float* train = (const float*)d_in[1];
  const float* acp = (const float*)d_in[2];
  const int* t = (const int*)d_in[3];
  float* out = (float*)d_out;
  float* wsf = (float*)d_ws;

  prep_kernel<<<CB, 64, 0, stream>>>(x, acp, t, wsf);
  norm_gemm_kernel<<<NPAD / NT1, 256, 0, stream>>>(x, train, wsf);
  softmax_kernel<<<CB, 1024, 0, stream>>>(wsf);
  gemm2_kernel<<<dim3(CD / TD2 / (TD2 / TD2) / 1 * 1 ? (CD / TD2) : (CD / TD2), G2), 256, 0, stream>>>(train, wsf);
  finalize_kernel<<<(CB * CD) / 256, 256, 0, stream>>>(x, wsf, out);
}